// Round 1
// baseline (777.443 us; speedup 1.0000x reference)
//
#include <hip/hip_runtime.h>
#include <cstdint>
#include <cstddef>

#define B_ 2
#define T_ 2048
#define D_ 2048
#define HQ_ 16
#define HKV_ 8
#define HD_ 128

typedef __attribute__((ext_vector_type(8))) short short8;
typedef __attribute__((ext_vector_type(8))) unsigned short ushort8;
typedef __attribute__((ext_vector_type(4))) float f32x4;
typedef __attribute__((ext_vector_type(2))) unsigned short ushort2v;
typedef __attribute__((ext_vector_type(4))) unsigned short ushort4v;
typedef __attribute__((ext_vector_type(2))) float float2v;
typedef __attribute__((ext_vector_type(4))) float float4v;

__device__ __forceinline__ unsigned short f2bf(float f) {
  unsigned int u = __builtin_bit_cast(unsigned int, f);
  u += 0x7fffu + ((u >> 16) & 1u);
  return (unsigned short)(u >> 16);
}
__device__ __forceinline__ float bf2f(unsigned short h) {
  unsigned int u = ((unsigned int)h) << 16;
  return __builtin_bit_cast(float, u);
}

// ---------------- cast f32 -> bf16 ----------------
__global__ __launch_bounds__(256) void cast_f32_bf16(const float* __restrict__ s,
                                                     unsigned short* __restrict__ d, int n) {
  int i = (blockIdx.x * 256 + threadIdx.x) * 4;
  if (i + 3 < n) {
    float4v v = *(const float4v*)(s + i);
    ushort4v o; o.x = f2bf(v.x); o.y = f2bf(v.y); o.z = f2bf(v.z); o.w = f2bf(v.w);
    *(ushort4v*)(d + i) = o;
  }
}

// ---------------- GEMM: C[M,N] = A[M,K] * W[N,K]^T (bf16 in, f32 acc) ----------------
// 128x128 tile, 4 waves (2x2), each wave 64x64 via 4x4 frags of 16x16x32 bf16 MFMA.
template<int M, int N, int K, bool BF16_OUT>
__global__ __launch_bounds__(256) void gemm_bt(const unsigned short* __restrict__ A,
                                               const unsigned short* __restrict__ W,
                                               void* __restrict__ Cout) {
  __shared__ __align__(16) unsigned short As[128 * 32];
  __shared__ __align__(16) unsigned short Bs[128 * 32];
  const int tid = threadIdx.x;
  const int lane = tid & 63;
  const int wv = tid >> 6;
  const int g = lane >> 4;
  const int c = lane & 15;
  const int m0 = blockIdx.y * 128;
  const int n0 = blockIdx.x * 128;
  const int wm = (wv >> 1) * 64;
  const int wn = (wv & 1) * 64;

  f32x4 acc[4][4];
  for (int i = 0; i < 4; i++)
    for (int j = 0; j < 4; j++) acc[i][j] = (f32x4)0.0f;

  // staging: 512 chunks of 16B per tile (128 rows x 32 cols bf16), 2 per thread
  const int ch0 = tid, ch1 = tid + 256;
  const int r0 = ch0 >> 2, cc0 = (ch0 & 3) * 8;
  const int r1 = ch1 >> 2, cc1 = (ch1 & 3) * 8;

  for (int k0 = 0; k0 < K; k0 += 32) {
    __syncthreads();
    *(ushort8*)&As[r0 * 32 + cc0] = *(const ushort8*)&A[(size_t)(m0 + r0) * K + k0 + cc0];
    *(ushort8*)&As[r1 * 32 + cc1] = *(const ushort8*)&A[(size_t)(m0 + r1) * K + k0 + cc1];
    *(ushort8*)&Bs[r0 * 32 + cc0] = *(const ushort8*)&W[(size_t)(n0 + r0) * K + k0 + cc0];
    *(ushort8*)&Bs[r1 * 32 + cc1] = *(const ushort8*)&W[(size_t)(n0 + r1) * K + k0 + cc1];
    __syncthreads();
    short8 a[4], b[4];
    for (int i = 0; i < 4; i++) a[i] = *(const short8*)&As[(wm + i * 16 + c) * 32 + g * 8];
    for (int j = 0; j < 4; j++) b[j] = *(const short8*)&Bs[(wn + j * 16 + c) * 32 + g * 8];
    for (int i = 0; i < 4; i++)
      for (int j = 0; j < 4; j++)
        acc[i][j] = __builtin_amdgcn_mfma_f32_16x16x32_bf16(a[i], b[j], acc[i][j], 0, 0, 0);
  }

  for (int i = 0; i < 4; i++)
    for (int j = 0; j < 4; j++)
      for (int r = 0; r < 4; r++) {
        int row = m0 + wm + i * 16 + g * 4 + r;
        int col = n0 + wn + j * 16 + c;
        if (BF16_OUT)
          ((unsigned short*)Cout)[(size_t)row * N + col] = f2bf(acc[i][j][r]);
        else
          ((float*)Cout)[(size_t)row * N + col] = acc[i][j][r];
      }
}

// ---------------- RMSNorm + RoPE for Q and K, relayout to (B,H,T,HD) bf16 ----------------
// one wave per (b,t,slot); slot 0..15 = Q head, 16..23 = K head
__global__ __launch_bounds__(256) void qk_norm_rope(const unsigned short* __restrict__ qkv,
                                                    const float* __restrict__ cosT,
                                                    const float* __restrict__ sinT,
                                                    const float* __restrict__ q_scale,
                                                    const float* __restrict__ k_scale,
                                                    unsigned short* __restrict__ Qb,
                                                    unsigned short* __restrict__ Kb) {
  const int tid = threadIdx.x;
  const int lane = tid & 63;
  const int wv = tid >> 6;
  const int wid = blockIdx.x * 4 + wv;
  const int row = wid / 24;  // b*T + t
  const int slot = wid - row * 24;
  const int b = row >> 11;
  const int t = row & 2047;
  const int d0 = lane * 2;
  const unsigned short* src =
      qkv + (size_t)row * 4096 + (slot < 16 ? slot * 128 : 2048 + (slot - 16) * 128);
  ushort2v u = *(const ushort2v*)&src[d0];
  float x0 = bf2f(u.x), x1 = bf2f(u.y);
  float ss = x0 * x0 + x1 * x1;
  ss += __shfl_xor(ss, 1);  ss += __shfl_xor(ss, 2);  ss += __shfl_xor(ss, 4);
  ss += __shfl_xor(ss, 8);  ss += __shfl_xor(ss, 16); ss += __shfl_xor(ss, 32);
  float rinv = rsqrtf(ss * (1.0f / 128.0f) + 1e-6f);
  const float* sc = (slot < 16) ? q_scale : k_scale;
  float2v scv = *(const float2v*)&sc[d0];
  float xn0 = x0 * rinv * scv.x;
  float xn1 = x1 * rinv * scv.y;
  float o0 = __shfl_xor(xn0, 32);
  float o1 = __shfl_xor(xn1, 32);
  float sgn = (lane < 32) ? -1.0f : 1.0f;  // rot[d<64] = -x[d+64]; rot[d>=64] = x[d-64]
  float2v cs = *(const float2v*)&cosT[t * 128 + d0];
  float2v sn = *(const float2v*)&sinT[t * 128 + d0];
  float r0v = xn0 * cs.x + sgn * o0 * sn.x;
  float r1v = xn1 * cs.y + sgn * o1 * sn.y;
  ushort2v out; out.x = f2bf(r0v); out.y = f2bf(r1v);
  unsigned short* dst;
  if (slot < 16) dst = Qb + ((size_t)(b * HQ_ + slot) * T_ + t) * HD_;
  else           dst = Kb + ((size_t)(b * HKV_ + (slot - 16)) * T_ + t) * HD_;
  *(ushort2v*)&dst[d0] = out;
}

// ---------------- V transpose: (b,t,kv,d) -> Vt[b,kv,d,t] bf16 ----------------
__global__ __launch_bounds__(256) void v_transpose(const unsigned short* __restrict__ qkv,
                                                   unsigned short* __restrict__ Vt) {
  __shared__ unsigned short lds[128 * 65];
  const int tid = threadIdx.x;
  const int blk = blockIdx.x;       // b*256 + kv*32 + tblk
  const int tblk = blk & 31;
  const int kv = (blk >> 5) & 7;
  const int b = blk >> 8;
  const int t0 = tblk * 64;
  const int r = tid >> 2;
  const int seg = tid & 3;
  const unsigned short* src = qkv + (size_t)(b * T_ + t0 + r) * 4096 + 3072 + kv * 128;
  for (int i = 0; i < 4; i++) {
    int cc = seg * 32 + i * 8;
    ushort8 v = *(const ushort8*)&src[cc];
    for (int q = 0; q < 8; q++) lds[(cc + q) * 65 + r] = v[q];
  }
  __syncthreads();
  const int cI = tid >> 1;
  const int rs = (tid & 1) * 32;
  unsigned short* dst = Vt + ((size_t)(b * HKV_ + kv) * HD_ + cI) * T_ + t0 + rs;
  const unsigned short* srow = &lds[cI * 65 + rs];
  for (int j = 0; j < 32; j += 4) {
    ushort4v v; v.x = srow[j]; v.y = srow[j + 1]; v.z = srow[j + 2]; v.w = srow[j + 3];
    *(ushort4v*)&dst[j] = v;
  }
}

// ---------------- Flash attention, causal, GQA (GROUP=2) ----------------
// one wave per (b,h,16-row Q tile); 32-key tiles; wave-private P through LDS
__global__ __launch_bounds__(256) void attn(const unsigned short* __restrict__ Qb,
                                            const unsigned short* __restrict__ Kb,
                                            const unsigned short* __restrict__ Vt,
                                            unsigned short* __restrict__ ctxb) {
  __shared__ __align__(16) unsigned short plds[4][16 * 32];
  const int tid = threadIdx.x;
  const int lane = tid & 63;
  const int wv = tid >> 6;
  const int g = lane >> 4;
  const int c = lane & 15;
  const int wid = blockIdx.x * 4 + wv;
  const int b = wid >> 11;
  const int h = (wid >> 7) & 15;
  const int qt = wid & 127;
  const int qbase = qt * 16;
  const int kv = h >> 1;

  const unsigned short* Qh = Qb + ((size_t)(b * HQ_ + h) * T_ + qbase) * HD_;
  const unsigned short* Kh = Kb + (size_t)(b * HKV_ + kv) * T_ * HD_;
  const unsigned short* Vh = Vt + (size_t)(b * HKV_ + kv) * HD_ * T_;

  short8 aq[4];
  for (int dk = 0; dk < 4; dk++) aq[dk] = *(const short8*)&Qh[c * HD_ + dk * 32 + g * 8];

  f32x4 acc[8];
  for (int i = 0; i < 8; i++) acc[i] = (f32x4)0.0f;
  float m_i[4], l_i[4];
  for (int r = 0; r < 4; r++) { m_i[r] = -1e30f; l_i[r] = 0.0f; }

  const int nkt = (qbase + 47) >> 5;  // ceil((qbase+16)/32)
  const float scale = 0.08838834764831845f;  // 1/sqrt(128)

  for (int kt = 0; kt < nkt; kt++) {
    f32x4 s0 = (f32x4)0.0f, s1 = (f32x4)0.0f;
    for (int dk = 0; dk < 4; dk++) {
      short8 b0 = *(const short8*)&Kh[(size_t)(kt * 32 + c) * HD_ + dk * 32 + g * 8];
      short8 b1 = *(const short8*)&Kh[(size_t)(kt * 32 + 16 + c) * HD_ + dk * 32 + g * 8];
      s0 = __builtin_amdgcn_mfma_f32_16x16x32_bf16(aq[dk], b0, s0, 0, 0, 0);
      s1 = __builtin_amdgcn_mfma_f32_16x16x32_bf16(aq[dk], b1, s1, 0, 0, 0);
    }
    const bool lastt = (kt == nkt - 1);
    for (int r = 0; r < 4; r++) {
      float v0 = s0[r] * scale, v1 = s1[r] * scale;
      if (lastt) {
        int rowa = qbase + g * 4 + r;
        if (kt * 32 + c > rowa) v0 = -1e30f;
        if (kt * 32 + 16 + c > rowa) v1 = -1e30f;
      }
      float tmax = fmaxf(v0, v1);
      tmax = fmaxf(tmax, __shfl_xor(tmax, 1));
      tmax = fmaxf(tmax, __shfl_xor(tmax, 2));
      tmax = fmaxf(tmax, __shfl_xor(tmax, 4));
      tmax = fmaxf(tmax, __shfl_xor(tmax, 8));
      float mn = fmaxf(m_i[r], tmax);
      float alpha = __expf(m_i[r] - mn);
      float p0 = __expf(v0 - mn);
      float p1 = __expf(v1 - mn);
      float ps = p0 + p1;
      ps += __shfl_xor(ps, 1); ps += __shfl_xor(ps, 2);
      ps += __shfl_xor(ps, 4); ps += __shfl_xor(ps, 8);
      l_i[r] = l_i[r] * alpha + ps;
      m_i[r] = mn;
      for (int dc = 0; dc < 8; dc++) acc[dc][r] *= alpha;
      plds[wv][(g * 4 + r) * 32 + c] = f2bf(p0);
      plds[wv][(g * 4 + r) * 32 + 16 + c] = f2bf(p1);
    }
    // C-layout -> A-layout round trip (wave-synchronous LDS, DS ops in-order per wave)
    short8 ap = *(const short8*)&plds[wv][c * 32 + g * 8];
    for (int dc = 0; dc < 8; dc++) {
      short8 bvf = *(const short8*)&Vh[(size_t)(dc * 16 + c) * T_ + kt * 32 + g * 8];
      acc[dc] = __builtin_amdgcn_mfma_f32_16x16x32_bf16(ap, bvf, acc[dc], 0, 0, 0);
    }
  }

  for (int r = 0; r < 4; r++) {
    float inv = 1.0f / l_i[r];
    int row = b * T_ + qbase + g * 4 + r;
    for (int dc = 0; dc < 8; dc++)
      ctxb[(size_t)row * (HQ_ * HD_) + h * HD_ + dc * 16 + c] = f2bf(acc[dc][r] * inv);
  }
}

extern "C" void kernel_launch(void* const* d_in, const int* in_sizes, int n_in,
                              void* d_out, int out_size, void* d_ws, size_t ws_size,
                              hipStream_t stream) {
  const float* x = (const float*)d_in[0];
  // d_in[1] = mask (unused; causal mask is structural)
  const float* cosT = (const float*)d_in[2];
  const float* sinT = (const float*)d_in[3];
  const float* Wq = (const float*)d_in[4];
  const float* Wk = (const float*)d_in[5];
  const float* Wv = (const float*)d_in[6];
  const float* Wo = (const float*)d_in[7];
  const float* q_scale = (const float*)d_in[8];
  const float* k_scale = (const float*)d_in[9];

  char* ws = (char*)d_ws;
  unsigned short* qkv  = (unsigned short*)(ws + 0);           // 4096x4096 bf16 (32MB)
  unsigned short* ctxb = qkv;                                  // alias: qkv dead before attn
  unsigned short* xb   = (unsigned short*)(ws + 33554432);     // 4096x2048 bf16
  unsigned short* wqkv = (unsigned short*)(ws + 50331648);     // 4096x2048 bf16
  unsigned short* wob  = (unsigned short*)(ws + 67108864);     // 2048x2048 bf16
  unsigned short* Qb   = (unsigned short*)(ws + 75497472);     // (B,HQ,T,HD) bf16
  unsigned short* Kb   = (unsigned short*)(ws + 92274688);     // (B,HKV,T,HD) bf16
  unsigned short* Vt   = (unsigned short*)(ws + 100663296);    // (B,HKV,HD,T) bf16
  // total: 109,051,904 bytes

  auto cgrid = [](int n) { return dim3((unsigned)((n / 4 + 255) / 256)); };
  cast_f32_bf16<<<cgrid(8388608), 256, 0, stream>>>(x, xb, 8388608);
  cast_f32_bf16<<<cgrid(4194304), 256, 0, stream>>>(Wq, wqkv, 4194304);
  cast_f32_bf16<<<cgrid(2097152), 256, 0, stream>>>(Wk, wqkv + 4194304, 2097152);
  cast_f32_bf16<<<cgrid(2097152), 256, 0, stream>>>(Wv, wqkv + 6291456, 2097152);
  cast_f32_bf16<<<cgrid(4194304), 256, 0, stream>>>(Wo, wob, 4194304);

  gemm_bt<4096, 4096, 2048, true><<<dim3(32, 32), 256, 0, stream>>>(xb, wqkv, qkv);
  qk_norm_rope<<<24576, 256, 0, stream>>>(qkv, cosT, sinT, q_scale, k_scale, Qb, Kb);
  v_transpose<<<512, 256, 0, stream>>>(qkv, Vt);
  attn<<<1024, 256, 0, stream>>>(Qb, Kb, Vt, ctxb);
  gemm_bt<4096, 2048, 2048, false><<<dim3(16, 32), 256, 0, stream>>>(ctxb, wob, d_out);
}

// Round 2
// 556.149 us; speedup vs baseline: 1.3979x; 1.3979x over previous
//
#include <hip/hip_runtime.h>
#include <cstdint>
#include <cstddef>

#define B_ 2
#define T_ 2048
#define D_ 2048
#define HQ_ 16
#define HKV_ 8
#define HD_ 128

typedef __attribute__((ext_vector_type(8))) short short8;
typedef __attribute__((ext_vector_type(8))) unsigned short ushort8;
typedef __attribute__((ext_vector_type(4))) float f32x4;
typedef __attribute__((ext_vector_type(2))) unsigned short ushort2v;
typedef __attribute__((ext_vector_type(4))) unsigned short ushort4v;
typedef __attribute__((ext_vector_type(2))) float float2v;
typedef __attribute__((ext_vector_type(4))) float float4v;

__device__ __forceinline__ unsigned short f2bf(float f) {
  unsigned int u = __builtin_bit_cast(unsigned int, f);
  u += 0x7fffu + ((u >> 16) & 1u);
  return (unsigned short)(u >> 16);
}
__device__ __forceinline__ float bf2f(unsigned short h) {
  unsigned int u = ((unsigned int)h) << 16;
  return __builtin_bit_cast(float, u);
}

// ---------------- cast f32 -> bf16 ----------------
__global__ __launch_bounds__(256) void cast_f32_bf16(const float* __restrict__ s,
                                                     unsigned short* __restrict__ d, int n) {
  int i = (blockIdx.x * 256 + threadIdx.x) * 4;
  if (i + 3 < n) {
    float4v v = *(const float4v*)(s + i);
    ushort4v o; o.x = f2bf(v.x); o.y = f2bf(v.y); o.z = f2bf(v.z); o.w = f2bf(v.w);
    *(ushort4v*)(d + i) = o;
  }
}

// ---------------- GEMM: C[M,N] = A[M,K] * W[N,K]^T (bf16 in, f32 acc) ----------------
// 128x128 tile, 4 waves (2x2), each wave 64x64 via 4x4 frags of 16x16x32 bf16 MFMA.
template<int M, int N, int K, bool BF16_OUT>
__global__ __launch_bounds__(256) void gemm_bt(const unsigned short* __restrict__ A,
                                               const unsigned short* __restrict__ W,
                                               void* __restrict__ Cout) {
  __shared__ __align__(16) unsigned short As[128 * 32];
  __shared__ __align__(16) unsigned short Bs[128 * 32];
  const int tid = threadIdx.x;
  const int lane = tid & 63;
  const int wv = tid >> 6;
  const int g = lane >> 4;
  const int c = lane & 15;
  const int m0 = blockIdx.y * 128;
  const int n0 = blockIdx.x * 128;
  const int wm = (wv >> 1) * 64;
  const int wn = (wv & 1) * 64;

  f32x4 acc[4][4];
  for (int i = 0; i < 4; i++)
    for (int j = 0; j < 4; j++) acc[i][j] = (f32x4)0.0f;

  const int ch0 = tid, ch1 = tid + 256;
  const int r0 = ch0 >> 2, cc0 = (ch0 & 3) * 8;
  const int r1 = ch1 >> 2, cc1 = (ch1 & 3) * 8;

  for (int k0 = 0; k0 < K; k0 += 32) {
    __syncthreads();
    *(ushort8*)&As[r0 * 32 + cc0] = *(const ushort8*)&A[(size_t)(m0 + r0) * K + k0 + cc0];
    *(ushort8*)&As[r1 * 32 + cc1] = *(const ushort8*)&A[(size_t)(m0 + r1) * K + k0 + cc1];
    *(ushort8*)&Bs[r0 * 32 + cc0] = *(const ushort8*)&W[(size_t)(n0 + r0) * K + k0 + cc0];
    *(ushort8*)&Bs[r1 * 32 + cc1] = *(const ushort8*)&W[(size_t)(n0 + r1) * K + k0 + cc1];
    __syncthreads();
    short8 a[4], b[4];
    for (int i = 0; i < 4; i++) a[i] = *(const short8*)&As[(wm + i * 16 + c) * 32 + g * 8];
    for (int j = 0; j < 4; j++) b[j] = *(const short8*)&Bs[(wn + j * 16 + c) * 32 + g * 8];
    for (int i = 0; i < 4; i++)
      for (int j = 0; j < 4; j++)
        acc[i][j] = __builtin_amdgcn_mfma_f32_16x16x32_bf16(a[i], b[j], acc[i][j], 0, 0, 0);
  }

  for (int i = 0; i < 4; i++)
    for (int j = 0; j < 4; j++)
      for (int r = 0; r < 4; r++) {
        int row = m0 + wm + i * 16 + g * 4 + r;
        int col = n0 + wn + j * 16 + c;
        if (BF16_OUT)
          ((unsigned short*)Cout)[(size_t)row * N + col] = f2bf(acc[i][j][r]);
        else
          ((float*)Cout)[(size_t)row * N + col] = acc[i][j][r];
      }
}

// ---------------- RMSNorm + RoPE for Q and K, relayout to (B,H,T,HD) bf16 ----------------
__global__ __launch_bounds__(256) void qk_norm_rope(const unsigned short* __restrict__ qkv,
                                                    const float* __restrict__ cosT,
                                                    const float* __restrict__ sinT,
                                                    const float* __restrict__ q_scale,
                                                    const float* __restrict__ k_scale,
                                                    unsigned short* __restrict__ Qb,
                                                    unsigned short* __restrict__ Kb) {
  const int tid = threadIdx.x;
  const int lane = tid & 63;
  const int wv = tid >> 6;
  const int wid = blockIdx.x * 4 + wv;
  const int row = wid / 24;  // b*T + t
  const int slot = wid - row * 24;
  const int b = row >> 11;
  const int t = row & 2047;
  const int d0 = lane * 2;
  const unsigned short* src =
      qkv + (size_t)row * 4096 + (slot < 16 ? slot * 128 : 2048 + (slot - 16) * 128);
  ushort2v u = *(const ushort2v*)&src[d0];
  float x0 = bf2f(u.x), x1 = bf2f(u.y);
  float ss = x0 * x0 + x1 * x1;
  ss += __shfl_xor(ss, 1);  ss += __shfl_xor(ss, 2);  ss += __shfl_xor(ss, 4);
  ss += __shfl_xor(ss, 8);  ss += __shfl_xor(ss, 16); ss += __shfl_xor(ss, 32);
  float rinv = rsqrtf(ss * (1.0f / 128.0f) + 1e-6f);
  const float* sc = (slot < 16) ? q_scale : k_scale;
  float2v scv = *(const float2v*)&sc[d0];
  float xn0 = x0 * rinv * scv.x;
  float xn1 = x1 * rinv * scv.y;
  float o0 = __shfl_xor(xn0, 32);
  float o1 = __shfl_xor(xn1, 32);
  float sgn = (lane < 32) ? -1.0f : 1.0f;
  float2v cs = *(const float2v*)&cosT[t * 128 + d0];
  float2v sn = *(const float2v*)&sinT[t * 128 + d0];
  float r0v = xn0 * cs.x + sgn * o0 * sn.x;
  float r1v = xn1 * cs.y + sgn * o1 * sn.y;
  ushort2v out; out.x = f2bf(r0v); out.y = f2bf(r1v);
  unsigned short* dst;
  if (slot < 16) dst = Qb + ((size_t)(b * HQ_ + slot) * T_ + t) * HD_;
  else           dst = Kb + ((size_t)(b * HKV_ + (slot - 16)) * T_ + t) * HD_;
  *(ushort2v*)&dst[d0] = out;
}

// ---------------- V transpose: (b,t,kv,d) -> Vt[b,kv,d,t] bf16 ----------------
__global__ __launch_bounds__(256) void v_transpose(const unsigned short* __restrict__ qkv,
                                                   unsigned short* __restrict__ Vt) {
  __shared__ unsigned short lds[128 * 65];
  const int tid = threadIdx.x;
  const int blk = blockIdx.x;
  const int tblk = blk & 31;
  const int kv = (blk >> 5) & 7;
  const int b = blk >> 8;
  const int t0 = tblk * 64;
  const int r = tid >> 2;
  const int seg = tid & 3;
  const unsigned short* src = qkv + (size_t)(b * T_ + t0 + r) * 4096 + 3072 + kv * 128;
  for (int i = 0; i < 4; i++) {
    int cc = seg * 32 + i * 8;
    ushort8 v = *(const ushort8*)&src[cc];
    for (int q = 0; q < 8; q++) lds[(cc + q) * 65 + r] = v[q];
  }
  __syncthreads();
  const int cI = tid >> 1;
  const int rs = (tid & 1) * 32;
  unsigned short* dst = Vt + ((size_t)(b * HKV_ + kv) * HD_ + cI) * T_ + t0 + rs;
  const unsigned short* srow = &lds[cI * 65 + rs];
  for (int j = 0; j < 32; j += 4) {
    ushort4v v; v.x = srow[j]; v.y = srow[j + 1]; v.z = srow[j + 2]; v.w = srow[j + 3];
    *(ushort4v*)&dst[j] = v;
  }
}

// ---------------- Flash attention v2: causal, GQA, balanced pairs, no-max softmax ----------------
// One wave per Q-tile pair (pr, 127-pr): constant ~65.5 key-tiles per wave.
// No online max (|s| <= sqrt(128) -> exp is f32-safe); l is a per-lane accumulator,
// reduced once per Q-tile. K double-buffered in registers (prefetch next tile).
__global__ __launch_bounds__(256) void attn(const unsigned short* __restrict__ Qb,
                                            const unsigned short* __restrict__ Kb,
                                            const unsigned short* __restrict__ Vt,
                                            unsigned short* __restrict__ ctxb) {
  __shared__ __align__(16) unsigned short plds[4][16 * 32];
  const int tid = threadIdx.x;
  const int lane = tid & 63;
  const int wv = tid >> 6;
  const int g = lane >> 4;
  const int c = lane & 15;

  // XCD swizzle: blk%8 picks the XCD (round-robin heuristic); give each XCD 2 (b,kv)
  // combos so its K/V working set (~2MB) fits the 4MB L2.
  const int blk = blockIdx.x;                       // 0..511
  const int j = blk >> 3;                           // 0..63
  const int combo = ((blk & 7) << 1) | (j >> 5);    // 0..15 = (b,kv)
  const int i = j & 31;                             // 0..31
  const int b = combo >> 3;
  const int kv = combo & 7;
  const int h = (kv << 1) | (i >> 4);
  const int pr = ((i & 15) << 2) | wv;              // 0..63

  const unsigned short* Kh = Kb + (size_t)(b * HKV_ + kv) * T_ * HD_;
  const unsigned short* Vh = Vt + (size_t)(b * HKV_ + kv) * HD_ * T_;
  const float scale = 0.08838834764831845f;  // 1/sqrt(128)

  short8 ka[8], kb2[8];

  for (int ph = 0; ph < 2; ph++) {
    const int qt = ph ? (127 - pr) : pr;
    const int nkt = (qt * 16 + 47) >> 5;
    const unsigned short* Qh = Qb + ((size_t)(b * HQ_ + h) * T_ + qt * 16) * HD_;

    short8 aq[4];
#pragma unroll
    for (int dk = 0; dk < 4; dk++) aq[dk] = *(const short8*)&Qh[c * HD_ + dk * 32 + g * 8];

    f32x4 acc[8];
#pragma unroll
    for (int dc = 0; dc < 8; dc++) acc[dc] = (f32x4)0.0f;
    float lp[4] = {0.0f, 0.0f, 0.0f, 0.0f};

    auto loadK = [&](short8* kr, int kt) {
      const unsigned short* kp = Kh + (size_t)(kt * 32 + c) * HD_ + g * 8;
#pragma unroll
      for (int dk = 0; dk < 4; dk++) {
        kr[2 * dk]     = *(const short8*)(kp + dk * 32);
        kr[2 * dk + 1] = *(const short8*)(kp + 16 * HD_ + dk * 32);
      }
    };

    auto body = [&](const short8* kr, int kt) {
      f32x4 s0 = (f32x4)0.0f, s1 = (f32x4)0.0f;
#pragma unroll
      for (int dk = 0; dk < 4; dk++) {
        s0 = __builtin_amdgcn_mfma_f32_16x16x32_bf16(aq[dk], kr[2 * dk], s0, 0, 0, 0);
        s1 = __builtin_amdgcn_mfma_f32_16x16x32_bf16(aq[dk], kr[2 * dk + 1], s1, 0, 0, 0);
      }
      short8 vr[8];
      const unsigned short* vp = Vh + (size_t)c * T_ + kt * 32 + g * 8;
#pragma unroll
      for (int dc = 0; dc < 8; dc++) vr[dc] = *(const short8*)(vp + (size_t)dc * 16 * T_);
      const bool lastt = (kt == nkt - 1);
#pragma unroll
      for (int r = 0; r < 4; r++) {
        float p0 = __expf(s0[r] * scale);
        float p1 = __expf(s1[r] * scale);
        if (lastt) {
          int rowa = qt * 16 + g * 4 + r;
          if (kt * 32 + c > rowa) p0 = 0.0f;
          if (kt * 32 + 16 + c > rowa) p1 = 0.0f;
        }
        lp[r] += p0 + p1;
        plds[wv][(g * 4 + r) * 32 + c] = f2bf(p0);
        plds[wv][(g * 4 + r) * 32 + 16 + c] = f2bf(p1);
      }
      short8 ap = *(const short8*)&plds[wv][c * 32 + g * 8];
#pragma unroll
      for (int dc = 0; dc < 8; dc++)
        acc[dc] = __builtin_amdgcn_mfma_f32_16x16x32_bf16(ap, vr[dc], acc[dc], 0, 0, 0);
    };

    loadK(ka, 0);
    int kt = 0;
    for (;;) {
      if (kt + 1 < nkt) loadK(kb2, kt + 1);
      body(ka, kt);
      if (++kt == nkt) break;
      if (kt + 1 < nkt) loadK(ka, kt + 1);
      body(kb2, kt);
      if (++kt == nkt) break;
    }

#pragma unroll
    for (int r = 0; r < 4; r++) {
      float l = lp[r];
      l += __shfl_xor(l, 1); l += __shfl_xor(l, 2);
      l += __shfl_xor(l, 4); l += __shfl_xor(l, 8);
      float inv = 1.0f / l;
      int row = b * T_ + qt * 16 + g * 4 + r;
#pragma unroll
      for (int dc = 0; dc < 8; dc++)
        ctxb[(size_t)row * (HQ_ * HD_) + h * HD_ + dc * 16 + c] = f2bf(acc[dc][r] * inv);
    }
  }
}

extern "C" void kernel_launch(void* const* d_in, const int* in_sizes, int n_in,
                              void* d_out, int out_size, void* d_ws, size_t ws_size,
                              hipStream_t stream) {
  const float* x = (const float*)d_in[0];
  const float* cosT = (const float*)d_in[2];
  const float* sinT = (const float*)d_in[3];
  const float* Wq = (const float*)d_in[4];
  const float* Wk = (const float*)d_in[5];
  const float* Wv = (const float*)d_in[6];
  const float* Wo = (const float*)d_in[7];
  const float* q_scale = (const float*)d_in[8];
  const float* k_scale = (const float*)d_in[9];

  char* ws = (char*)d_ws;
  unsigned short* qkv  = (unsigned short*)(ws + 0);
  unsigned short* ctxb = qkv;                                  // alias: qkv dead before attn
  unsigned short* xb   = (unsigned short*)(ws + 33554432);
  unsigned short* wqkv = (unsigned short*)(ws + 50331648);
  unsigned short* wob  = (unsigned short*)(ws + 67108864);
  unsigned short* Qb   = (unsigned short*)(ws + 75497472);
  unsigned short* Kb   = (unsigned short*)(ws + 92274688);
  unsigned short* Vt   = (unsigned short*)(ws + 100663296);

  auto cgrid = [](int n) { return dim3((unsigned)((n / 4 + 255) / 256)); };
  cast_f32_bf16<<<cgrid(8388608), 256, 0, stream>>>(x, xb, 8388608);
  cast_f32_bf16<<<cgrid(4194304), 256, 0, stream>>>(Wq, wqkv, 4194304);
  cast_f32_bf16<<<cgrid(2097152), 256, 0, stream>>>(Wk, wqkv + 4194304, 2097152);
  cast_f32_bf16<<<cgrid(2097152), 256, 0, stream>>>(Wv, wqkv + 6291456, 2097152);
  cast_f32_bf16<<<cgrid(4194304), 256, 0, stream>>>(Wo, wob, 4194304);

  gemm_bt<4096, 4096, 2048, true><<<dim3(32, 32), 256, 0, stream>>>(xb, wqkv, qkv);
  qk_norm_rope<<<24576, 256, 0, stream>>>(qkv, cosT, sinT, q_scale, k_scale, Qb, Kb);
  v_transpose<<<512, 256, 0, stream>>>(qkv, Vt);
  attn<<<512, 256, 0, stream>>>(Qb, Kb, Vt, ctxb);
  gemm_bt<4096, 2048, 2048, false><<<dim3(16, 32), 256, 0, stream>>>(ctxb, wob, d_out);
}

// Round 3
// 389.758 us; speedup vs baseline: 1.9947x; 1.4269x over previous
//
#include <hip/hip_runtime.h>
#include <cstdint>
#include <cstddef>

#define B_ 2
#define T_ 2048
#define D_ 2048
#define HQ_ 16
#define HKV_ 8
#define HD_ 128

typedef __attribute__((ext_vector_type(8))) short short8;
typedef __attribute__((ext_vector_type(8))) unsigned short ushort8;
typedef __attribute__((ext_vector_type(4))) float f32x4;
typedef __attribute__((ext_vector_type(2))) unsigned short ushort2v;
typedef __attribute__((ext_vector_type(4))) unsigned short ushort4v;
typedef __attribute__((ext_vector_type(2))) float float2v;
typedef __attribute__((ext_vector_type(4))) float float4v;

__device__ __forceinline__ unsigned short f2bf(float f) {
  unsigned int u = __builtin_bit_cast(unsigned int, f);
  u += 0x7fffu + ((u >> 16) & 1u);
  return (unsigned short)(u >> 16);
}
__device__ __forceinline__ float bf2f(unsigned short h) {
  unsigned int u = ((unsigned int)h) << 16;
  return __builtin_bit_cast(float, u);
}

#if defined(__has_builtin)
#if __has_builtin(__builtin_amdgcn_global_load_lds)
#define HAS_GLL 1
#endif
#endif
#ifndef HAS_GLL
#define HAS_GLL 0
#endif

// async global->LDS, 16B per lane; LDS dest = base (wave-uniform) + lane*16
__device__ __forceinline__ void gll16(const void* g, void* l) {
#if HAS_GLL
  __builtin_amdgcn_global_load_lds((const __attribute__((address_space(1))) void*)g,
                                   (__attribute__((address_space(3))) void*)l, 16, 0, 0);
#else
  *(ushort8*)((char*)l + (threadIdx.x & 63) * 16) = *(const ushort8*)g;
#endif
}

// ---------------- cast f32 -> bf16 ----------------
__global__ __launch_bounds__(256) void cast_f32_bf16(const float* __restrict__ s,
                                                     unsigned short* __restrict__ d, int n) {
  int i = (blockIdx.x * 256 + threadIdx.x) * 4;
  if (i + 3 < n) {
    float4v v = *(const float4v*)(s + i);
    ushort4v o; o.x = f2bf(v.x); o.y = f2bf(v.y); o.z = f2bf(v.z); o.w = f2bf(v.w);
    *(ushort4v*)(d + i) = o;
  }
}

// ---------------- GEMM: C[M,N] = A[M,K] * W[N,K]^T, m97-style async staging ----------------
template<int M, int N, int K, bool BF16_OUT>
__global__ __launch_bounds__(256) void gemm_bt(const unsigned short* __restrict__ A,
                                               const unsigned short* __restrict__ W,
                                               void* __restrict__ Cout) {
  __shared__ __align__(16) unsigned short As[128 * 32];
  __shared__ __align__(16) unsigned short Bs[128 * 32];
  const int tid = threadIdx.x;
  const int lane = tid & 63;
  const int wv = tid >> 6;
  const int g = lane >> 4;
  const int c = lane & 15;
  const int m0 = blockIdx.y * 128;
  const int n0 = blockIdx.x * 128;
  const int wm = (wv >> 1) * 64;
  const int wn = (wv & 1) * 64;

  f32x4 acc[4][4];
  for (int i = 0; i < 4; i++)
    for (int j = 0; j < 4; j++) acc[i][j] = (f32x4)0.0f;

  // 512 16B chunks per 128x32 tile; wave stages 64-chunk runs (contiguous LDS)
  const int ch0 = wv * 64 + lane;
  const int r0 = ch0 >> 2, cc0 = (ch0 & 3) * 8;
  const int ch1 = 256 + ch0;
  const int r1 = ch1 >> 2, cc1 = (ch1 & 3) * 8;
  unsigned short* ldsA0 = As + (size_t)(wv * 64) * 8;
  unsigned short* ldsA1 = As + (size_t)(256 + wv * 64) * 8;
  unsigned short* ldsB0 = Bs + (size_t)(wv * 64) * 8;
  unsigned short* ldsB1 = Bs + (size_t)(256 + wv * 64) * 8;

  for (int k0 = 0; k0 < K; k0 += 32) {
    __syncthreads();
    gll16(&A[(size_t)(m0 + r0) * K + k0 + cc0], ldsA0);
    gll16(&A[(size_t)(m0 + r1) * K + k0 + cc1], ldsA1);
    gll16(&W[(size_t)(n0 + r0) * K + k0 + cc0], ldsB0);
    gll16(&W[(size_t)(n0 + r1) * K + k0 + cc1], ldsB1);
    __syncthreads();
    short8 a[4], b[4];
    for (int i = 0; i < 4; i++) a[i] = *(const short8*)&As[(wm + i * 16 + c) * 32 + g * 8];
    for (int j = 0; j < 4; j++) b[j] = *(const short8*)&Bs[(wn + j * 16 + c) * 32 + g * 8];
    for (int i = 0; i < 4; i++)
      for (int j = 0; j < 4; j++)
        acc[i][j] = __builtin_amdgcn_mfma_f32_16x16x32_bf16(a[i], b[j], acc[i][j], 0, 0, 0);
  }

  for (int i = 0; i < 4; i++)
    for (int j = 0; j < 4; j++)
      for (int r = 0; r < 4; r++) {
        int row = m0 + wm + i * 16 + g * 4 + r;
        int col = n0 + wn + j * 16 + c;
        if (BF16_OUT)
          ((unsigned short*)Cout)[(size_t)row * N + col] = f2bf(acc[i][j][r]);
        else
          ((float*)Cout)[(size_t)row * N + col] = acc[i][j][r];
      }
}

// ---------------- RMSNorm + RoPE for Q and K, relayout to (B,H,T,HD) bf16 ----------------
__global__ __launch_bounds__(256) void qk_norm_rope(const unsigned short* __restrict__ qkv,
                                                    const float* __restrict__ cosT,
                                                    const float* __restrict__ sinT,
                                                    const float* __restrict__ q_scale,
                                                    const float* __restrict__ k_scale,
                                                    unsigned short* __restrict__ Qb,
                                                    unsigned short* __restrict__ Kb) {
  const int tid = threadIdx.x;
  const int lane = tid & 63;
  const int wv = tid >> 6;
  const int wid = blockIdx.x * 4 + wv;
  const int row = wid / 24;  // b*T + t
  const int slot = wid - row * 24;
  const int b = row >> 11;
  const int t = row & 2047;
  const int d0 = lane * 2;
  const unsigned short* src =
      qkv + (size_t)row * 4096 + (slot < 16 ? slot * 128 : 2048 + (slot - 16) * 128);
  ushort2v u = *(const ushort2v*)&src[d0];
  float x0 = bf2f(u.x), x1 = bf2f(u.y);
  float ss = x0 * x0 + x1 * x1;
  ss += __shfl_xor(ss, 1);  ss += __shfl_xor(ss, 2);  ss += __shfl_xor(ss, 4);
  ss += __shfl_xor(ss, 8);  ss += __shfl_xor(ss, 16); ss += __shfl_xor(ss, 32);
  float rinv = rsqrtf(ss * (1.0f / 128.0f) + 1e-6f);
  const float* sc = (slot < 16) ? q_scale : k_scale;
  float2v scv = *(const float2v*)&sc[d0];
  float xn0 = x0 * rinv * scv.x;
  float xn1 = x1 * rinv * scv.y;
  float o0 = __shfl_xor(xn0, 32);
  float o1 = __shfl_xor(xn1, 32);
  float sgn = (lane < 32) ? -1.0f : 1.0f;
  float2v cs = *(const float2v*)&cosT[t * 128 + d0];
  float2v sn = *(const float2v*)&sinT[t * 128 + d0];
  float r0v = xn0 * cs.x + sgn * o0 * sn.x;
  float r1v = xn1 * cs.y + sgn * o1 * sn.y;
  ushort2v out; out.x = f2bf(r0v); out.y = f2bf(r1v);
  unsigned short* dst;
  if (slot < 16) dst = Qb + ((size_t)(b * HQ_ + slot) * T_ + t) * HD_;
  else           dst = Kb + ((size_t)(b * HKV_ + (slot - 16)) * T_ + t) * HD_;
  *(ushort2v*)&dst[d0] = out;
}

// ---------------- V transpose: (b,t,kv,d) -> Vt[b,kv,d,t] bf16 ----------------
__global__ __launch_bounds__(256) void v_transpose(const unsigned short* __restrict__ qkv,
                                                   unsigned short* __restrict__ Vt) {
  __shared__ unsigned short lds[128 * 65];
  const int tid = threadIdx.x;
  const int blk = blockIdx.x;
  const int tblk = blk & 31;
  const int kv = (blk >> 5) & 7;
  const int b = blk >> 8;
  const int t0 = tblk * 64;
  const int r = tid >> 2;
  const int seg = tid & 3;
  const unsigned short* src = qkv + (size_t)(b * T_ + t0 + r) * 4096 + 3072 + kv * 128;
  for (int i = 0; i < 4; i++) {
    int cc = seg * 32 + i * 8;
    ushort8 v = *(const ushort8*)&src[cc];
    for (int q = 0; q < 8; q++) lds[(cc + q) * 65 + r] = v[q];
  }
  __syncthreads();
  const int cI = tid >> 1;
  const int rs = (tid & 1) * 32;
  unsigned short* dst = Vt + ((size_t)(b * HKV_ + kv) * HD_ + cI) * T_ + t0 + rs;
  const unsigned short* srow = &lds[cI * 65 + rs];
  for (int j = 0; j < 32; j += 4) {
    ushort4v v; v.x = srow[j]; v.y = srow[j + 1]; v.z = srow[j + 2]; v.w = srow[j + 3];
    *(ushort4v*)&dst[j] = v;
  }
}

// ---------------- Flash attention v3: block-cooperative, LDS-staged K/V ----------------
// Block = 4 waves = one (b,h) and a causal pair of 64-row Q blocks (p, 31-p):
// exactly 33 key-tiles of 64 keys per block. K/V staged via async global_load_lds,
// shared by all 4 waves (4x traffic cut vs per-wave loads). XOR swizzle (16B chunks,
// applied to the GLOBAL source address so LDS dest stays lane-contiguous) makes all
// ds_read_b128 fragment reads <=2-way bank-aliased (free). No-max softmax as in v2.
__global__ __launch_bounds__(256) void attn(const unsigned short* __restrict__ Qb,
                                            const unsigned short* __restrict__ Kb,
                                            const unsigned short* __restrict__ Vt,
                                            unsigned short* __restrict__ ctxb) {
  __shared__ __align__(16) unsigned short Ks[64 * 128];   // [key][hd], chunk-swizzled
  __shared__ __align__(16) unsigned short Vs[128 * 64];   // [hd][key], chunk-swizzled
  __shared__ __align__(16) unsigned short Ps[4][16 * 72]; // per-wave P, stride 72 (pad)
  const int tid = threadIdx.x;
  const int lane = tid & 63;
  const int wv = tid >> 6;
  const int g = lane >> 4;
  const int c = lane & 15;

  // blk&7 = kv: assuming blk%8 -> XCD round-robin, each XCD's L2 holds one kv's
  // K+V (2MB, both b) for the whole kernel.
  const int blk = blockIdx.x;            // 0..511
  const int kv = blk & 7;
  const int idx = blk >> 3;              // 0..63
  const int p = idx >> 2;                // 0..15 pair index
  const int b = (idx >> 1) & 1;
  const int h = kv * 2 + (idx & 1);

  const unsigned short* Kh = Kb + (size_t)(b * HKV_ + kv) * T_ * HD_;
  const unsigned short* Vh = Vt + (size_t)(b * HKV_ + kv) * HD_ * T_;
  const float scale = 0.08838834764831845f;  // 1/sqrt(128)

  for (int ph = 0; ph < 2; ph++) {
    const int qb = ph ? (31 - p) : p;    // 64-row q-block index
    const int nkt = qb + 1;              // 64-key tiles (last = diagonal)
    const unsigned short* Qh = Qb + ((size_t)(b * HQ_ + h) * T_ + qb * 64 + wv * 16) * HD_;

    short8 aq[4];
#pragma unroll
    for (int dk = 0; dk < 4; dk++) aq[dk] = *(const short8*)&Qh[c * HD_ + dk * 32 + g * 8];

    f32x4 acc[8];
#pragma unroll
    for (int dc = 0; dc < 8; dc++) acc[dc] = (f32x4)0.0f;
    float lp[4] = {0.0f, 0.0f, 0.0f, 0.0f};

    for (int kt = 0; kt < nkt; kt++) {
      __syncthreads();  // previous tile's LDS reads done
      // stage K (64x128, 1024 chunks) + V (128x64) ; wave stages chunks [wv*256,+256)
#pragma unroll
      for (int i = 0; i < 4; i++) {
        const int ch = wv * 256 + i * 64 + lane;
        const int rowK = ch >> 4, ccK = ch & 15;
        const int sK = ccK ^ (rowK & 7);
        gll16(Kh + (size_t)(kt * 64 + rowK) * HD_ + sK * 8,
              Ks + (size_t)(wv * 256 + i * 64) * 8);
        const int rowV = ch >> 3, ccV = ch & 7;
        const int sV = ccV ^ (rowV & 7);
        gll16(Vh + (size_t)rowV * T_ + kt * 64 + sV * 8,
              Vs + (size_t)(wv * 256 + i * 64) * 8);
      }
      __syncthreads();  // staging visible (compiler adds vmcnt(0) drain)

      // QK^T: 16 rows x 64 keys
      f32x4 s[4];
#pragma unroll
      for (int kf = 0; kf < 4; kf++) s[kf] = (f32x4)0.0f;
#pragma unroll
      for (int dk = 0; dk < 4; dk++) {
#pragma unroll
        for (int kf = 0; kf < 4; kf++) {
          short8 bk = *(const short8*)&Ks[(kf * 16 + c) * 128 + ((dk * 4 + g) ^ (c & 7)) * 8];
          s[kf] = __builtin_amdgcn_mfma_f32_16x16x32_bf16(aq[dk], bk, s[kf], 0, 0, 0);
        }
      }

      const bool diag = (kt == nkt - 1);
#pragma unroll
      for (int kf = 0; kf < 4; kf++) {
#pragma unroll
        for (int r = 0; r < 4; r++) {
          float pv = __expf(s[kf][r] * scale);
          if (diag) {
            int key = kt * 64 + kf * 16 + c;
            int rowq = qb * 64 + wv * 16 + g * 4 + r;
            if (key > rowq) pv = 0.0f;
          }
          lp[r] += pv;
          Ps[wv][(g * 4 + r) * 72 + kf * 16 + c] = f2bf(pv);
        }
      }

      // C-layout -> A-layout round trip (wave-private, DS in-order per wave)
      short8 ap[2];
      ap[0] = *(const short8*)&Ps[wv][c * 72 + g * 8];
      ap[1] = *(const short8*)&Ps[wv][c * 72 + 32 + g * 8];
#pragma unroll
      for (int dc = 0; dc < 8; dc++) {
#pragma unroll
        for (int kf2 = 0; kf2 < 2; kf2++) {
          short8 bv = *(const short8*)&Vs[(dc * 16 + c) * 64 + ((kf2 * 4 + g) ^ (c & 7)) * 8];
          acc[dc] = __builtin_amdgcn_mfma_f32_16x16x32_bf16(ap[kf2], bv, acc[dc], 0, 0, 0);
        }
      }
    }

#pragma unroll
    for (int r = 0; r < 4; r++) {
      float l = lp[r];
      l += __shfl_xor(l, 1); l += __shfl_xor(l, 2);
      l += __shfl_xor(l, 4); l += __shfl_xor(l, 8);
      float inv = 1.0f / l;
      int row = b * T_ + qb * 64 + wv * 16 + g * 4 + r;
#pragma unroll
      for (int dc = 0; dc < 8; dc++)
        ctxb[(size_t)row * (HQ_ * HD_) + h * HD_ + dc * 16 + c] = f2bf(acc[dc][r] * inv);
    }
  }
}

extern "C" void kernel_launch(void* const* d_in, const int* in_sizes, int n_in,
                              void* d_out, int out_size, void* d_ws, size_t ws_size,
                              hipStream_t stream) {
  const float* x = (const float*)d_in[0];
  const float* cosT = (const float*)d_in[2];
  const float* sinT = (const float*)d_in[3];
  const float* Wq = (const float*)d_in[4];
  const float* Wk = (const float*)d_in[5];
  const float* Wv = (const float*)d_in[6];
  const float* Wo = (const float*)d_in[7];
  const float* q_scale = (const float*)d_in[8];
  const float* k_scale = (const float*)d_in[9];

  char* ws = (char*)d_ws;
  unsigned short* qkv  = (unsigned short*)(ws + 0);
  unsigned short* ctxb = qkv;                                  // alias: qkv dead before attn
  unsigned short* xb   = (unsigned short*)(ws + 33554432);
  unsigned short* wqkv = (unsigned short*)(ws + 50331648);
  unsigned short* wob  = (unsigned short*)(ws + 67108864);
  unsigned short* Qb   = (unsigned short*)(ws + 75497472);
  unsigned short* Kb   = (unsigned short*)(ws + 92274688);
  unsigned short* Vt   = (unsigned short*)(ws + 100663296);

  auto cgrid = [](int n) { return dim3((unsigned)((n / 4 + 255) / 256)); };
  cast_f32_bf16<<<cgrid(8388608), 256, 0, stream>>>(x, xb, 8388608);
  cast_f32_bf16<<<cgrid(4194304), 256, 0, stream>>>(Wq, wqkv, 4194304);
  cast_f32_bf16<<<cgrid(2097152), 256, 0, stream>>>(Wk, wqkv + 4194304, 2097152);
  cast_f32_bf16<<<cgrid(2097152), 256, 0, stream>>>(Wv, wqkv + 6291456, 2097152);
  cast_f32_bf16<<<cgrid(4194304), 256, 0, stream>>>(Wo, wob, 4194304);

  gemm_bt<4096, 4096, 2048, true><<<dim3(32, 32), 256, 0, stream>>>(xb, wqkv, qkv);
  qk_norm_rope<<<24576, 256, 0, stream>>>(qkv, cosT, sinT, q_scale, k_scale, Qb, Kb);
  v_transpose<<<512, 256, 0, stream>>>(qkv, Vt);
  attn<<<512, 256, 0, stream>>>(Qb, Kb, Vt, ctxb);
  gemm_bt<4096, 2048, 2048, false><<<dim3(16, 32), 256, 0, stream>>>(ctxb, wob, d_out);
}

// Round 4
// 373.544 us; speedup vs baseline: 2.0813x; 1.0434x over previous
//
#include <hip/hip_runtime.h>
#include <cstdint>
#include <cstddef>

#define B_ 2
#define T_ 2048
#define D_ 2048
#define HQ_ 16
#define HKV_ 8
#define HD_ 128

typedef __attribute__((ext_vector_type(8))) short short8;
typedef __attribute__((ext_vector_type(8))) unsigned short ushort8;
typedef __attribute__((ext_vector_type(4))) float f32x4;
typedef __attribute__((ext_vector_type(2))) unsigned short ushort2v;
typedef __attribute__((ext_vector_type(4))) unsigned short ushort4v;
typedef __attribute__((ext_vector_type(2))) float float2v;
typedef __attribute__((ext_vector_type(4))) float float4v;

__device__ __forceinline__ unsigned short f2bf(float f) {
  unsigned int u = __builtin_bit_cast(unsigned int, f);
  u += 0x7fffu + ((u >> 16) & 1u);
  return (unsigned short)(u >> 16);
}
__device__ __forceinline__ float bf2f(unsigned short h) {
  unsigned int u = ((unsigned int)h) << 16;
  return __builtin_bit_cast(float, u);
}

#if defined(__has_builtin)
#if __has_builtin(__builtin_amdgcn_global_load_lds)
#define HAS_GLL 1
#endif
#endif
#ifndef HAS_GLL
#define HAS_GLL 0
#endif

// async global->LDS, 16B per lane; LDS dest = base (wave-uniform) + lane*16
__device__ __forceinline__ void gll16(const void* g, void* l) {
#if HAS_GLL
  __builtin_amdgcn_global_load_lds((const __attribute__((address_space(1))) void*)g,
                                   (__attribute__((address_space(3))) void*)l, 16, 0, 0);
#else
  *(ushort8*)((char*)l + (threadIdx.x & 63) * 16) = *(const ushort8*)g;
#endif
}

// ---------------- fused cast f32 -> bf16 for all five tensors (one launch) ----------------
// element ranges: [0,8388608) x -> xb ; [8388608,16777216) Wq|Wk|Wv -> wqkv (contiguous dst) ;
// [16777216,20971520) Wo -> wob
__global__ __launch_bounds__(256) void cast_all(const float* __restrict__ x,
                                                const float* __restrict__ wq,
                                                const float* __restrict__ wk,
                                                const float* __restrict__ wv,
                                                const float* __restrict__ wo,
                                                unsigned short* __restrict__ xb,
                                                unsigned short* __restrict__ wqkv,
                                                unsigned short* __restrict__ wob) {
  int i = (blockIdx.x * 256 + threadIdx.x) * 4;
  if (i >= 20971520) return;
  const float* s;
  unsigned short* d;
  int soff, doff;
  if (i < 8388608)       { s = x;  soff = i;            d = xb;   doff = i; }
  else if (i < 12582912) { s = wq; soff = i - 8388608;  d = wqkv; doff = i - 8388608; }
  else if (i < 14680064) { s = wk; soff = i - 12582912; d = wqkv; doff = i - 8388608; }
  else if (i < 16777216) { s = wv; soff = i - 14680064; d = wqkv; doff = i - 8388608; }
  else                   { s = wo; soff = i - 16777216; d = wob;  doff = i - 16777216; }
  float4v v = *(const float4v*)(s + soff);
  ushort4v o; o.x = f2bf(v.x); o.y = f2bf(v.y); o.z = f2bf(v.z); o.w = f2bf(v.w);
  *(ushort4v*)(d + doff) = o;
}

// ---------------- GEMM: C[M,N] = A[M,K] * W[N,K]^T, m97-style async staging ----------------
template<int M, int N, int K, bool BF16_OUT>
__global__ __launch_bounds__(256) void gemm_bt(const unsigned short* __restrict__ A,
                                               const unsigned short* __restrict__ W,
                                               void* __restrict__ Cout) {
  __shared__ __align__(16) unsigned short As[128 * 32];
  __shared__ __align__(16) unsigned short Bs[128 * 32];
  const int tid = threadIdx.x;
  const int lane = tid & 63;
  const int wv = tid >> 6;
  const int g = lane >> 4;
  const int c = lane & 15;
  const int m0 = blockIdx.y * 128;
  const int n0 = blockIdx.x * 128;
  const int wm = (wv >> 1) * 64;
  const int wn = (wv & 1) * 64;

  f32x4 acc[4][4];
  for (int i = 0; i < 4; i++)
    for (int j = 0; j < 4; j++) acc[i][j] = (f32x4)0.0f;

  const int ch0 = wv * 64 + lane;
  const int r0 = ch0 >> 2, cc0 = (ch0 & 3) * 8;
  const int ch1 = 256 + ch0;
  const int r1 = ch1 >> 2, cc1 = (ch1 & 3) * 8;
  unsigned short* ldsA0 = As + (size_t)(wv * 64) * 8;
  unsigned short* ldsA1 = As + (size_t)(256 + wv * 64) * 8;
  unsigned short* ldsB0 = Bs + (size_t)(wv * 64) * 8;
  unsigned short* ldsB1 = Bs + (size_t)(256 + wv * 64) * 8;

  for (int k0 = 0; k0 < K; k0 += 32) {
    __syncthreads();
    gll16(&A[(size_t)(m0 + r0) * K + k0 + cc0], ldsA0);
    gll16(&A[(size_t)(m0 + r1) * K + k0 + cc1], ldsA1);
    gll16(&W[(size_t)(n0 + r0) * K + k0 + cc0], ldsB0);
    gll16(&W[(size_t)(n0 + r1) * K + k0 + cc1], ldsB1);
    __syncthreads();
    short8 a[4], b[4];
    for (int i = 0; i < 4; i++) a[i] = *(const short8*)&As[(wm + i * 16 + c) * 32 + g * 8];
    for (int j = 0; j < 4; j++) b[j] = *(const short8*)&Bs[(wn + j * 16 + c) * 32 + g * 8];
    for (int i = 0; i < 4; i++)
      for (int j = 0; j < 4; j++)
        acc[i][j] = __builtin_amdgcn_mfma_f32_16x16x32_bf16(a[i], b[j], acc[i][j], 0, 0, 0);
  }

  for (int i = 0; i < 4; i++)
    for (int j = 0; j < 4; j++)
      for (int r = 0; r < 4; r++) {
        int row = m0 + wm + i * 16 + g * 4 + r;
        int col = n0 + wn + j * 16 + c;
        if (BF16_OUT)
          ((unsigned short*)Cout)[(size_t)row * N + col] = f2bf(acc[i][j][r]);
        else
          ((float*)Cout)[(size_t)row * N + col] = acc[i][j][r];
      }
}

// ---------------- RMSNorm + RoPE v2: one block per (b,t), cos/sin in regs ----------------
// Each of 4 waves handles 6 of the 24 slots (16 Q heads + 8 K heads) for this token.
__global__ __launch_bounds__(256) void qk_norm_rope(const unsigned short* __restrict__ qkv,
                                                    const float* __restrict__ cosT,
                                                    const float* __restrict__ sinT,
                                                    const float* __restrict__ q_scale,
                                                    const float* __restrict__ k_scale,
                                                    unsigned short* __restrict__ Qb,
                                                    unsigned short* __restrict__ Kb) {
  const int tid = threadIdx.x;
  const int lane = tid & 63;
  const int wv = tid >> 6;
  const int row = blockIdx.x;   // b*T + t
  const int b = row >> 11;
  const int t = row & 2047;
  const int d0 = lane * 2;

  const float2v cs = *(const float2v*)&cosT[t * 128 + d0];
  const float2v sn = *(const float2v*)&sinT[t * 128 + d0];
  const float2v qsc = *(const float2v*)&q_scale[d0];
  const float2v ksc = *(const float2v*)&k_scale[d0];
  const float sgn = (lane < 32) ? -1.0f : 1.0f;
  const unsigned short* base = qkv + (size_t)row * 4096;

#pragma unroll
  for (int s6 = 0; s6 < 6; s6++) {
    const int slot = wv * 6 + s6;
    const bool isQ = slot < 16;
    const unsigned short* src = base + (isQ ? slot * 128 : 2048 + (slot - 16) * 128);
    ushort2v u = *(const ushort2v*)&src[d0];
    float x0 = bf2f(u.x), x1 = bf2f(u.y);
    float ss = x0 * x0 + x1 * x1;
    ss += __shfl_xor(ss, 1);  ss += __shfl_xor(ss, 2);  ss += __shfl_xor(ss, 4);
    ss += __shfl_xor(ss, 8);  ss += __shfl_xor(ss, 16); ss += __shfl_xor(ss, 32);
    float rinv = rsqrtf(ss * (1.0f / 128.0f) + 1e-6f);
    float2v scv = isQ ? qsc : ksc;
    float xn0 = x0 * rinv * scv.x;
    float xn1 = x1 * rinv * scv.y;
    float o0 = __shfl_xor(xn0, 32);
    float o1 = __shfl_xor(xn1, 32);
    float r0v = xn0 * cs.x + sgn * o0 * sn.x;
    float r1v = xn1 * cs.y + sgn * o1 * sn.y;
    ushort2v out; out.x = f2bf(r0v); out.y = f2bf(r1v);
    unsigned short* dst;
    if (isQ) dst = Qb + ((size_t)(b * HQ_ + slot) * T_ + t) * HD_;
    else     dst = Kb + ((size_t)(b * HKV_ + (slot - 16)) * T_ + t) * HD_;
    *(ushort2v*)&dst[d0] = out;
  }
}

// ---------------- V transpose: (b,t,kv,d) -> Vt[b,kv,d,t] bf16 ----------------
__global__ __launch_bounds__(256) void v_transpose(const unsigned short* __restrict__ qkv,
                                                   unsigned short* __restrict__ Vt) {
  __shared__ unsigned short lds[128 * 65];
  const int tid = threadIdx.x;
  const int blk = blockIdx.x;
  const int tblk = blk & 31;
  const int kv = (blk >> 5) & 7;
  const int b = blk >> 8;
  const int t0 = tblk * 64;
  const int r = tid >> 2;
  const int seg = tid & 3;
  const unsigned short* src = qkv + (size_t)(b * T_ + t0 + r) * 4096 + 3072 + kv * 128;
  for (int i = 0; i < 4; i++) {
    int cc = seg * 32 + i * 8;
    ushort8 v = *(const ushort8*)&src[cc];
    for (int q = 0; q < 8; q++) lds[(cc + q) * 65 + r] = v[q];
  }
  __syncthreads();
  const int cI = tid >> 1;
  const int rs = (tid & 1) * 32;
  unsigned short* dst = Vt + ((size_t)(b * HKV_ + kv) * HD_ + cI) * T_ + t0 + rs;
  const unsigned short* srow = &lds[cI * 65 + rs];
  for (int j = 0; j < 32; j += 4) {
    ushort4v v; v.x = srow[j]; v.y = srow[j + 1]; v.z = srow[j + 2]; v.w = srow[j + 3];
    *(ushort4v*)&dst[j] = v;
  }
}

// ---------------- Flash attention v3: block-cooperative, LDS-staged K/V ----------------
__global__ __launch_bounds__(256) void attn(const unsigned short* __restrict__ Qb,
                                            const unsigned short* __restrict__ Kb,
                                            const unsigned short* __restrict__ Vt,
                                            unsigned short* __restrict__ ctxb) {
  __shared__ __align__(16) unsigned short Ks[64 * 128];   // [key][hd], chunk-swizzled
  __shared__ __align__(16) unsigned short Vs[128 * 64];   // [hd][key], chunk-swizzled
  __shared__ __align__(16) unsigned short Ps[4][16 * 72]; // per-wave P, stride 72 (pad)
  const int tid = threadIdx.x;
  const int lane = tid & 63;
  const int wv = tid >> 6;
  const int g = lane >> 4;
  const int c = lane & 15;

  const int blk = blockIdx.x;            // 0..511
  const int kv = blk & 7;
  const int idx = blk >> 3;              // 0..63
  const int p = idx >> 2;                // 0..15 pair index
  const int b = (idx >> 1) & 1;
  const int h = kv * 2 + (idx & 1);

  const unsigned short* Kh = Kb + (size_t)(b * HKV_ + kv) * T_ * HD_;
  const unsigned short* Vh = Vt + (size_t)(b * HKV_ + kv) * HD_ * T_;
  const float scale = 0.08838834764831845f;  // 1/sqrt(128)

  for (int ph = 0; ph < 2; ph++) {
    const int qb = ph ? (31 - p) : p;    // 64-row q-block index
    const int nkt = qb + 1;
    const unsigned short* Qh = Qb + ((size_t)(b * HQ_ + h) * T_ + qb * 64 + wv * 16) * HD_;

    short8 aq[4];
#pragma unroll
    for (int dk = 0; dk < 4; dk++) aq[dk] = *(const short8*)&Qh[c * HD_ + dk * 32 + g * 8];

    f32x4 acc[8];
#pragma unroll
    for (int dc = 0; dc < 8; dc++) acc[dc] = (f32x4)0.0f;
    float lp[4] = {0.0f, 0.0f, 0.0f, 0.0f};

    for (int kt = 0; kt < nkt; kt++) {
      __syncthreads();
#pragma unroll
      for (int i = 0; i < 4; i++) {
        const int ch = wv * 256 + i * 64 + lane;
        const int rowK = ch >> 4, ccK = ch & 15;
        const int sK = ccK ^ (rowK & 7);
        gll16(Kh + (size_t)(kt * 64 + rowK) * HD_ + sK * 8,
              Ks + (size_t)(wv * 256 + i * 64) * 8);
        const int rowV = ch >> 3, ccV = ch & 7;
        const int sV = ccV ^ (rowV & 7);
        gll16(Vh + (size_t)rowV * T_ + kt * 64 + sV * 8,
              Vs + (size_t)(wv * 256 + i * 64) * 8);
      }
      __syncthreads();

      f32x4 s[4];
#pragma unroll
      for (int kf = 0; kf < 4; kf++) s[kf] = (f32x4)0.0f;
#pragma unroll
      for (int dk = 0; dk < 4; dk++) {
#pragma unroll
        for (int kf = 0; kf < 4; kf++) {
          short8 bk = *(const short8*)&Ks[(kf * 16 + c) * 128 + ((dk * 4 + g) ^ (c & 7)) * 8];
          s[kf] = __builtin_amdgcn_mfma_f32_16x16x32_bf16(aq[dk], bk, s[kf], 0, 0, 0);
        }
      }

      const bool diag = (kt == nkt - 1);
#pragma unroll
      for (int kf = 0; kf < 4; kf++) {
#pragma unroll
        for (int r = 0; r < 4; r++) {
          float pv = __expf(s[kf][r] * scale);
          if (diag) {
            int key = kt * 64 + kf * 16 + c;
            int rowq = qb * 64 + wv * 16 + g * 4 + r;
            if (key > rowq) pv = 0.0f;
          }
          lp[r] += pv;
          Ps[wv][(g * 4 + r) * 72 + kf * 16 + c] = f2bf(pv);
        }
      }

      short8 ap[2];
      ap[0] = *(const short8*)&Ps[wv][c * 72 + g * 8];
      ap[1] = *(const short8*)&Ps[wv][c * 72 + 32 + g * 8];
#pragma unroll
      for (int dc = 0; dc < 8; dc++) {
#pragma unroll
        for (int kf2 = 0; kf2 < 2; kf2++) {
          short8 bv = *(const short8*)&Vs[(dc * 16 + c) * 64 + ((kf2 * 4 + g) ^ (c & 7)) * 8];
          acc[dc] = __builtin_amdgcn_mfma_f32_16x16x32_bf16(ap[kf2], bv, acc[dc], 0, 0, 0);
        }
      }
    }

#pragma unroll
    for (int r = 0; r < 4; r++) {
      float l = lp[r];
      l += __shfl_xor(l, 1); l += __shfl_xor(l, 2);
      l += __shfl_xor(l, 4); l += __shfl_xor(l, 8);
      float inv = 1.0f / l;
      int row = b * T_ + qb * 64 + wv * 16 + g * 4 + r;
#pragma unroll
      for (int dc = 0; dc < 8; dc++)
        ctxb[(size_t)row * (HQ_ * HD_) + h * HD_ + dc * 16 + c] = f2bf(acc[dc][r] * inv);
    }
  }
}

extern "C" void kernel_launch(void* const* d_in, const int* in_sizes, int n_in,
                              void* d_out, int out_size, void* d_ws, size_t ws_size,
                              hipStream_t stream) {
  const float* x = (const float*)d_in[0];
  const float* cosT = (const float*)d_in[2];
  const float* sinT = (const float*)d_in[3];
  const float* Wq = (const float*)d_in[4];
  const float* Wk = (const float*)d_in[5];
  const float* Wv = (const float*)d_in[6];
  const float* Wo = (const float*)d_in[7];
  const float* q_scale = (const float*)d_in[8];
  const float* k_scale = (const float*)d_in[9];

  char* ws = (char*)d_ws;
  unsigned short* qkv  = (unsigned short*)(ws + 0);
  unsigned short* ctxb = qkv;                                  // alias: qkv dead before attn
  unsigned short* xb   = (unsigned short*)(ws + 33554432);
  unsigned short* wqkv = (unsigned short*)(ws + 50331648);
  unsigned short* wob  = (unsigned short*)(ws + 67108864);
  unsigned short* Qb   = (unsigned short*)(ws + 75497472);
  unsigned short* Kb   = (unsigned short*)(ws + 92274688);
  unsigned short* Vt   = (unsigned short*)(ws + 100663296);

  cast_all<<<20480, 256, 0, stream>>>(x, Wq, Wk, Wv, Wo, xb, wqkv, wob);
  gemm_bt<4096, 4096, 2048, true><<<dim3(32, 32), 256, 0, stream>>>(xb, wqkv, qkv);
  qk_norm_rope<<<4096, 256, 0, stream>>>(qkv, cosT, sinT, q_scale, k_scale, Qb, Kb);
  v_transpose<<<512, 256, 0, stream>>>(qkv, Vt);
  attn<<<512, 256, 0, stream>>>(Qb, Kb, Vt, ctxb);
  gemm_bt<4096, 2048, 2048, false><<<dim3(16, 32), 256, 0, stream>>>(ctxb, wob, d_out);
}